// Round 1
// baseline (563.653 us; speedup 1.0000x reference)
//
#include <hip/hip_runtime.h>
#include <hip/hip_bf16.h>

typedef __attribute__((ext_vector_type(4))) float  f32x4;
typedef __attribute__((ext_vector_type(8))) short  bf16x8;
typedef __attribute__((ext_vector_type(4))) float  float4v;
typedef __attribute__((ext_vector_type(8))) unsigned short ushort8;

#define CIO 128           // C_IN == C_OUT == 128
#define BM  64            // m-rows per block

__device__ __forceinline__ unsigned short f2bf(float f) {
  // round-to-nearest-even fp32 -> bf16
  unsigned int u = __float_as_uint(f);
  u = u + 0x7fffu + ((u >> 16) & 1u);
  return (unsigned short)(u >> 16);
}

// ---- prep: Wt[k][cout][cin] (bf16) = W[k][cin][cout] (fp32) ----
__global__ void prep_weights(const float* __restrict__ W,
                             unsigned short* __restrict__ Wt, int total) {
  int idx = blockIdx.x * 256 + threadIdx.x;
  if (idx >= total) return;
  int k  = idx >> 14;          // /16384
  int n  = (idx >> 7) & 127;   // cout  (row of Wt)
  int kk = idx & 127;          // cin   (col of Wt)
  Wt[idx] = f2bf(W[k * 16384 + kk * 128 + n]);
}

// ---- init: out[n][c] = bias[c] ----
__global__ void init_bias(float* __restrict__ out,
                          const float* __restrict__ bias, int total4) {
  int idx = blockIdx.x * 256 + threadIdx.x;
  if (idx >= total4) return;
  float4v b = ((const float4v*)bias)[idx & 31];   // 32 float4 per 128-col row
  ((float4v*)out)[idx] = b;
}

// ---- main: per offset k, gathered GEMM + scatter-add ----
__global__ __launch_bounds__(256) void spconv_mfma(
    const float* __restrict__ features,
    const unsigned short* __restrict__ Wt,   // [KVOL][128][128] bf16, [cout][cin]
    const int* __restrict__ in_map,
    const int* __restrict__ out_map,
    float* __restrict__ out,
    int M) {
  const int ky  = blockIdx.y;
  const int m0  = blockIdx.x * BM;
  const int tid = threadIdx.x;

  __shared__ unsigned short Alds[BM * CIO];    // 16 KB, XOR-swizzled rows
  __shared__ unsigned short Blds[CIO * CIO];   // 32 KB, XOR-swizzled rows

  // ---- stage B: coalesced copy of Wt[ky], swizzle on write ----
  {
    const ushort8* src = (const ushort8*)(Wt + ky * 16384);
    #pragma unroll
    for (int i = 0; i < 8; ++i) {
      int chunk = tid + i * 256;        // 2048 chunks of 16B
      int byte  = chunk * 16;
      int row   = byte >> 8;            // cout row (256B rows)
      int off   = byte & 255;
      int sw    = off ^ ((row & 7) << 4);
      *(ushort8*)((char*)Blds + row * 256 + sw) = src[chunk];
    }
  }

  // ---- stage A: gather 64 feature rows, fp32->bf16, swizzle on write ----
  {
    int r = tid >> 2;        // row 0..63
    int q = tid & 3;         // quarter of the 128 channels
    int m = m0 + r;
    unsigned short tmp[32];
    if (m < M) {
      int frow = in_map[ky * M + m];
      const float4v* src = (const float4v*)(features + frow * CIO + q * 32);
      #pragma unroll
      for (int i = 0; i < 8; ++i) {
        float4v v = src[i];
        tmp[i * 4 + 0] = f2bf(v.x);
        tmp[i * 4 + 1] = f2bf(v.y);
        tmp[i * 4 + 2] = f2bf(v.z);
        tmp[i * 4 + 3] = f2bf(v.w);
      }
    } else {
      #pragma unroll
      for (int i = 0; i < 32; ++i) tmp[i] = 0;
    }
    #pragma unroll
    for (int c = 0; c < 4; ++c) {
      int off = q * 64 + c * 16;
      int sw  = off ^ ((r & 7) << 4);
      *(ushort8*)((char*)Alds + r * 256 + sw) = *(ushort8*)(tmp + c * 8);
    }
  }
  __syncthreads();

  // ---- MFMA: 4 waves in 2x2 grid, each wave 32(m) x 64(n) ----
  const int wid  = tid >> 6;
  const int lane = tid & 63;
  const int wm   = wid >> 1;        // 0..1
  const int wn   = wid & 1;         // 0..1
  const int l16  = lane & 15;
  const int lk   = lane >> 4;       // 0..3  (k-octet selector)

  f32x4 acc[2][4] = {};
  #pragma unroll
  for (int kb = 0; kb < CIO; kb += 32) {
    bf16x8 af[2], bfr[4];
    #pragma unroll
    for (int mf = 0; mf < 2; ++mf) {
      int row = wm * 32 + mf * 16 + l16;
      int off = (kb + lk * 8) * 2;
      int sw  = off ^ ((row & 7) << 4);
      af[mf]  = *(const bf16x8*)((const char*)Alds + row * 256 + sw);
    }
    #pragma unroll
    for (int nf = 0; nf < 4; ++nf) {
      int n   = wn * 64 + nf * 16 + l16;
      int off = (kb + lk * 8) * 2;
      int sw  = off ^ ((n & 7) << 4);
      bfr[nf] = *(const bf16x8*)((const char*)Blds + n * 256 + sw);
    }
    #pragma unroll
    for (int mf = 0; mf < 2; ++mf)
      #pragma unroll
      for (int nf = 0; nf < 4; ++nf)
        acc[mf][nf] = __builtin_amdgcn_mfma_f32_16x16x32_bf16(
            af[mf], bfr[nf], acc[mf][nf], 0, 0, 0);
  }

  // ---- scatter-add: D row=(lane>>4)*4+reg, col=lane&15 (m89 layout) ----
  #pragma unroll
  for (int mf = 0; mf < 2; ++mf) {
    #pragma unroll
    for (int r = 0; r < 4; ++r) {
      int mrow = wm * 32 + mf * 16 + lk * 4 + r;
      int m    = m0 + mrow;
      if (m < M) {
        int orow   = out_map[ky * M + m];
        float* dst = out + orow * CIO + wn * 64 + l16;
        #pragma unroll
        for (int nf = 0; nf < 4; ++nf)
          unsafeAtomicAdd(dst + nf * 16, acc[mf][nf][r]);
      }
    }
  }
}

extern "C" void kernel_launch(void* const* d_in, const int* in_sizes, int n_in,
                              void* d_out, int out_size, void* d_ws, size_t ws_size,
                              hipStream_t stream) {
  const float* features = (const float*)d_in[0];
  const float* W        = (const float*)d_in[1];
  const float* bias     = (const float*)d_in[2];
  const int*   in_map   = (const int*)d_in[3];
  const int*   out_map  = (const int*)d_in[4];
  float*       out      = (float*)d_out;

  const int KVOL = in_sizes[1] / (CIO * CIO);       // 27
  const int M    = in_sizes[3] / KVOL;              // 50000

  unsigned short* Wt = (unsigned short*)d_ws;
  const size_t need = (size_t)KVOL * CIO * CIO * sizeof(unsigned short);
  if (ws_size < need) return;  // fail loudly (validation) rather than corrupt

  int wtot = KVOL * CIO * CIO;
  prep_weights<<<(wtot + 255) / 256, 256, 0, stream>>>(W, Wt, wtot);

  int total4 = out_size / 4;
  init_bias<<<(total4 + 255) / 256, 256, 0, stream>>>(out, bias, total4);

  dim3 grid((M + BM - 1) / BM, KVOL);
  spconv_mfma<<<grid, 256, 0, stream>>>(features, Wt, in_map, out_map, out, M);
}